// Round 9
// baseline (621.073 us; speedup 1.0000x reference)
//
#include <hip/hip_runtime.h>
#include <hip/hip_bf16.h>
#include <math.h>

#define NTOK 8192
#define DIM  1024
#define HDIM 512
#define KTOP 100
#define CHUNK 1024
#define KTH_RANK 2457   // threshold = 2457th-largest of Acmb == sort_asc[5735]
#define EQCAP 2048
#define PADK 0x3FFFFFFFu   // key_of(-2.0f): below every real key (|A|<=1)

typedef float f32x4 __attribute__((ext_vector_type(4)));
typedef short bf16x8 __attribute__((ext_vector_type(8)));
typedef unsigned int u32;
typedef unsigned short u16;

// ---- monotone float<->uint key (order-preserving) ----
__device__ __forceinline__ unsigned key_of(float f) {
  unsigned u = __float_as_uint(f);
  return (u & 0x80000000u) ? ~u : (u | 0x80000000u);
}
__device__ __forceinline__ float float_of_key(unsigned key) {
  unsigned u = (key & 0x80000000u) ? (key ^ 0x80000000u) : ~key;
  return __uint_as_float(u);
}
// ---- bf16 round-to-nearest-even helpers ----
__device__ __forceinline__ u16 bf16_rn(float x) {
  unsigned u = __float_as_uint(x);
  return (u16)((u + 0x7FFFu + ((u >> 16) & 1u)) >> 16);
}
__device__ __forceinline__ float bf16f(u16 h) {
  return __uint_as_float(((unsigned)h) << 16);
}
// ---- async global->LDS 16B ----
__device__ __forceinline__ void gload16(const void* gptr, void* lptr) {
  __builtin_amdgcn_global_load_lds(
      (const __attribute__((address_space(1))) u32*)gptr,
      (__attribute__((address_space(3))) u32*)lptr, 16, 0, 0);
}

// ============================================================
// Unified split-bf16 NT GEMM, 2-phase double-buffered, BK=32.
// C = (Ahi+Alo).(Bhi+Blo)^T.  512 thr (8 waves 2x4), wave tile
// (FM*16) x 32, tile BM=FM*32 x 128.  LDS rows 64B; XOR swizzle
// quad ^= ((row>>1)&3) applied on BOTH the (pre-swizzled) write
// side and the frag reads -> conflict-free b128 (verified r8: 0).
// MODE 0: A/B from bf16 hi/lo pairs via gload_lds;
//         Cf = acc * rq[row]*rk[col]  (folded normalization)
// MODE 1/2: A = Xf fp32, split hi/lo IN-REGISTER during staging
//         (ds_write, same swizzle); B via gload_lds.
//         t=tanh(acc+bias); MODE1: Cf=t + split out; MODE2: split only.
// ============================================================
template<int MODE, int FM>
__global__ __launch_bounds__(512, 4) void gemm_hl(
    const float* __restrict__ Xf,
    const u16* __restrict__ Ahi, const u16* __restrict__ Alo,
    const u16* __restrict__ Bhi, const u16* __restrict__ Blo,
    float* __restrict__ Cf, u16* __restrict__ Chi, u16* __restrict__ Clo,
    const float* __restrict__ bias,
    const float* __restrict__ rq, const float* __restrict__ rk,
    int K, int ldc)
{
  constexpr int BM = FM * 32;
  constexpr int RT = 2 * BM + 256;
  __shared__ __align__(16) short lds[2][RT * 32];

  const int tid = threadIdx.x, lane = tid & 63, wave = tid >> 6;
  const int wm = wave >> 2, wn = wave & 3;

  const int nwg = gridDim.x * gridDim.y;
  const int lin = blockIdx.y * gridDim.x + blockIdx.x;
  const int cpx = nwg >> 3;
  const int swz = (lin & 7) * cpx + (lin >> 3);
  const int bx = swz % gridDim.x, by = swz / gridDim.x;
  const int bm = by * BM, bn = bx * 128;

  f32x4 acc[FM][2] = {};

  auto STAGE = [&](int buf, int k0) {
    if constexpr (MODE == 0) {
      constexpr int RPW = RT / 8;
      constexpr int NI = RPW / 16;
#pragma unroll
      for (int j = 0; j < NI; ++j) {
        int rg = wave * RPW + j * 16;
        int r  = rg + (lane >> 2);
        const u16* gp; size_t grow;
        if (rg < BM)                { gp = Ahi; grow = (size_t)(bm + r); }
        else if (rg < 2 * BM)       { gp = Alo; grow = (size_t)(bm + r - BM); }
        else if (rg < 2 * BM + 128) { gp = Bhi; grow = (size_t)(bn + r - 2 * BM); }
        else                        { gp = Blo; grow = (size_t)(bn + r - 2 * BM - 128); }
        int ks = k0 + (((lane & 3) ^ ((r >> 1) & 3)) << 3);
        gload16(gp + grow * (size_t)K + ks, &lds[buf][rg * 32]);
      }
    } else {
      // B rows (2*BM..2*BM+255): 8 waves x 32 rows via gload_lds
#pragma unroll
      for (int j = 0; j < 2; ++j) {
        int rg = 2 * BM + wave * 32 + j * 16;
        int r  = rg + (lane >> 2);
        const u16* gp; size_t grow;
        if (rg < 2 * BM + 128) { gp = Bhi; grow = (size_t)(bn + r - 2 * BM); }
        else                   { gp = Blo; grow = (size_t)(bn + r - 2 * BM - 128); }
        int ks = k0 + (((lane & 3) ^ ((r >> 1) & 3)) << 3);
        gload16(gp + grow * (size_t)K + ks, &lds[buf][rg * 32]);
      }
      // A rows (0..BM-1): fp32 x -> hi/lo in-register -> swizzled ds_write
      // (BM=64: 512 thr x 1 float4 covers 64 rows x 32 k)
      int row = tid >> 3, k4 = (tid & 7) * 4;
      float4 v = *(const float4*)&Xf[(size_t)(bm + row) * K + k0 + k4];
      u16 h0 = bf16_rn(v.x), h1 = bf16_rn(v.y), h2 = bf16_rn(v.z), h3 = bf16_rn(v.w);
      u16 l0 = bf16_rn(v.x - bf16f(h0)), l1 = bf16_rn(v.y - bf16f(h1));
      u16 l2 = bf16_rn(v.z - bf16f(h2)), l3 = bf16_rn(v.w - bf16f(h3));
      int q = ((k4 >> 3) ^ ((row >> 1) & 3));
      int eoff = row * 32 + q * 8 + (k4 & 7);
      *(ushort4*)&lds[buf][eoff]           = make_ushort4(h0, h1, h2, h3);
      *(ushort4*)&lds[buf][BM * 32 + eoff] = make_ushort4(l0, l1, l2, l3);
    }
  };

  STAGE(0, 0);
  __syncthreads();
  const int NT = K / 32;
  int cur = 0;
  for (int t = 0; t < NT; ++t) {
    if (t + 1 < NT) STAGE(cur ^ 1, (t + 1) * 32);
    const short* L = lds[cur];
    const int qb = lane >> 4;
    bf16x8 ah[FM], al[FM], bh[2], bl[2];
#pragma unroll
    for (int m = 0; m < FM; ++m) {
      int r = wm * (FM * 16) + m * 16 + (lane & 15);
      int off = r * 32 + ((qb ^ ((r >> 1) & 3)) << 3);
      ah[m] = *(const bf16x8*)&L[off];
      al[m] = *(const bf16x8*)&L[BM * 32 + off];
    }
#pragma unroll
    for (int n = 0; n < 2; ++n) {
      int r = wn * 32 + n * 16 + (lane & 15);
      int off = r * 32 + ((qb ^ ((r >> 1) & 3)) << 3);
      bh[n] = *(const bf16x8*)&L[2 * BM * 32 + off];
      bl[n] = *(const bf16x8*)&L[(2 * BM + 128) * 32 + off];
    }
#pragma unroll
    for (int n = 0; n < 2; ++n)
#pragma unroll
      for (int m = 0; m < FM; ++m) {
        acc[m][n] = __builtin_amdgcn_mfma_f32_16x16x32_bf16(ah[m], bh[n], acc[m][n], 0, 0, 0);
        acc[m][n] = __builtin_amdgcn_mfma_f32_16x16x32_bf16(ah[m], bl[n], acc[m][n], 0, 0, 0);
        acc[m][n] = __builtin_amdgcn_mfma_f32_16x16x32_bf16(al[m], bh[n], acc[m][n], 0, 0, 0);
      }
    __syncthreads();
    cur ^= 1;
  }

#pragma unroll
  for (int m = 0; m < FM; ++m) {
    int rbase = bm + wm * (FM * 16) + m * 16 + (lane >> 4) * 4;
#pragma unroll
    for (int n = 0; n < 2; ++n) {
      int col = bn + wn * 32 + n * 16 + (lane & 15);
      if (MODE == 0) {
        float cs = rk[col];
#pragma unroll
        for (int r = 0; r < 4; ++r)
          Cf[(size_t)(rbase + r) * ldc + col] = acc[m][n][r] * rq[rbase + r] * cs;
      } else {
        float b = bias[col];
#pragma unroll
        for (int r = 0; r < 4; ++r) {
          size_t idx = (size_t)(rbase + r) * ldc + col;
          float t = tanhf(acc[m][n][r] + b);
          if (MODE == 1) Cf[idx] = t;
          u16 h = bf16_rn(t);
          Chi[idx] = h;
          Clo[idx] = bf16_rn(t - bf16f(h));
        }
      }
    }
  }
}

// ============================================================
__global__ __launch_bounds__(256) void wt_cast(
    const float* __restrict__ W, u16* __restrict__ Thi, u16* __restrict__ Tlo)
{
  __shared__ float t[32][33];
  const int bx = blockIdx.x, by = blockIdx.y;
  const int r = threadIdx.x >> 5, c = threadIdx.x & 31;
#pragma unroll
  for (int i = 0; i < 4; ++i)
    t[r + i * 8][c] = W[(size_t)(by * 32 + r + i * 8) * HDIM + bx * 32 + c];
  __syncthreads();
#pragma unroll
  for (int i = 0; i < 4; ++i) {
    int n = bx * 32 + r + i * 8, k = by * 32 + c;
    float v = t[c][r + i * 8];
    u16 h = bf16_rn(v);
    Thi[(size_t)n * DIM + k] = h;
    Tlo[(size_t)n * DIM + k] = bf16_rn(v - bf16f(h));
  }
}

// ============================================================
__global__ __launch_bounds__(256) void rownorm_inv(
    const u16* __restrict__ qh, const u16* __restrict__ ql,
    const u16* __restrict__ kh, const u16* __restrict__ kl,
    float* __restrict__ rq, float* __restrict__ rk)
{
  const int half = blockIdx.x >> 11;
  const int row = (blockIdx.x & 2047) * 4 + (threadIdx.x >> 6);
  const int lane = threadIdx.x & 63;
  const u16* hi = half ? kh : qh;
  const u16* lo = half ? kl : ql;
  size_t base = (size_t)row * HDIM + lane * 8;
  ushort4 h0 = *(const ushort4*)&hi[base], h1 = *(const ushort4*)&hi[base + 4];
  ushort4 l0 = *(const ushort4*)&lo[base], l1 = *(const ushort4*)&lo[base + 4];
  float f[8] = {bf16f(h0.x)+bf16f(l0.x), bf16f(h0.y)+bf16f(l0.y),
                bf16f(h0.z)+bf16f(l0.z), bf16f(h0.w)+bf16f(l0.w),
                bf16f(h1.x)+bf16f(l1.x), bf16f(h1.y)+bf16f(l1.y),
                bf16f(h1.z)+bf16f(l1.z), bf16f(h1.w)+bf16f(l1.w)};
  float ss = 0.f;
#pragma unroll
  for (int j = 0; j < 8; ++j) ss += f[j] * f[j];
#pragma unroll
  for (int off = 32; off > 0; off >>= 1) ss += __shfl_xor(ss, off);
  if (lane == 0) {
    float r = 1.0f / fmaxf(sqrtf(ss), 1e-12f);
    (half ? rk : rq)[row] = r;
  }
}

// ============================================================
// Per-row exact top-100, barrier-minimized (unchanged from round 7).
// ============================================================
__global__ __launch_bounds__(256) void topk_acmb(
    const float* __restrict__ Arows, const float* __restrict__ WA_w,
    const float* __restrict__ WA_b, float* __restrict__ Acmb, int row_base)
{
  __shared__ u32 hist[2048];      // 4096 bins, 2 x 16-bit counts per u32
  __shared__ u32 eqbuf[EQCAP];
  __shared__ u32 grbuf[128];
  __shared__ u32 tsum[256], tabove[256];
  __shared__ u32 s_b, s_need, s_cb, s_b2, s_need2, s_cb2, s_cg, s_ce;

  const int tid = threadIdx.x;
  const float4* src = (const float4*)(Arows + (size_t)blockIdx.x * NTOK);

  for (int i = tid; i < 2048; i += 256) hist[i] = 0u;
  if (tid == 0) { s_cg = 0u; s_ce = 0u; }

  u32 keys[32];
#pragma unroll
  for (int i = 0; i < 8; ++i) {
    float4 v = src[i * 256 + tid];
    keys[i * 4 + 0] = key_of(v.x);
    keys[i * 4 + 1] = key_of(v.y);
    keys[i * 4 + 2] = key_of(v.z);
    keys[i * 4 + 3] = key_of(v.w);
  }
  __syncthreads();

#pragma unroll
  for (int j = 0; j < 32; ++j) {
    u32 bin = keys[j] >> 20;
    atomicAdd(&hist[bin >> 1], (bin & 1) ? 0x10000u : 1u);
  }
  __syncthreads();

  auto scan12 = [&](u32 needK, u32* ob, u32* oneed, u32* ocb) {
    u32 cnt[16]; u32 mysum = 0;
#pragma unroll
    for (int i = 0; i < 8; ++i) {
      u32 pk = hist[tid * 8 + i];
      u32 c0 = pk & 0xFFFFu, c1 = pk >> 16;
      cnt[2 * i] = c0; cnt[2 * i + 1] = c1; mysum += c0 + c1;
    }
    tsum[tid] = mysum;
    __syncthreads();
    if (tid < 64) {
      u32 s0 = tsum[tid * 4], s1 = tsum[tid * 4 + 1];
      u32 s2 = tsum[tid * 4 + 2], s3 = tsum[tid * 4 + 3];
      u32 lsum = s0 + s1 + s2 + s3;
      u32 suf = lsum;
#pragma unroll
      for (int d = 1; d < 64; d <<= 1) {
        u32 v = (u32)__shfl_down((int)suf, d);
        if (tid + d < 64) suf += v;
      }
      u32 above = suf - lsum;
      tabove[tid * 4 + 3] = above;
      tabove[tid * 4 + 2] = above + s3;
      tabove[tid * 4 + 1] = above + s3 + s2;
      tabove[tid * 4 + 0] = above + s3 + s2 + s1;
    }
    __syncthreads();
    u32 above = tabove[tid];
#pragma unroll
    for (int b = 15; b >= 0; --b) {
      u32 c = cnt[b];
      if (above < needK && above + c >= needK) {
        *ob = (u32)(tid * 16 + b); *oneed = needK - above; *ocb = c;
      }
      above += c;
    }
    __syncthreads();
  };
  scan12(KTOP, &s_b, &s_need, &s_cb);

  const u32 b1 = s_b;
  const u32 need1 = s_need, cb1 = s_cb;
  const bool two = (cb1 > EQCAP);
  u32 b2v = 0, needF = need1;
  if (two) {
    for (int i = tid; i < 2048; i += 256) hist[i] = 0u;
    __syncthreads();
#pragma unroll
    for (int j = 0; j < 32; ++j) {
      u32 k = keys[j];
      if ((k >> 20) == b1) {
        u32 bin = (k >> 8) & 0xFFFu;
        atomicAdd(&hist[bin >> 1], (bin & 1) ? 0x10000u : 1u);
      }
    }
    __syncthreads();
    scan12(need1, &s_b2, &s_need2, &s_cb2);
    b2v = s_b2; needF = s_need2;
  }

#pragma unroll
  for (int j = 0; j < 32; ++j) {
    u32 k = keys[j];
    u32 hi12 = k >> 20;
    bool g = hi12 > b1, e = (hi12 == b1);
    if (two) {
      u32 mid = (k >> 8) & 0xFFFu;
      g = g || (e && mid > b2v);
      e = e && (mid == b2v);
    }
    if (g) { u32 p = atomicAdd(&s_cg, 1u); if (p < 128u) grbuf[p] = k; }
    else if (e) { u32 p = atomicAdd(&s_ce, 1u); if (p < EQCAP) eqbuf[p] = k; }
  }
  __syncthreads();

  const u32 cg = s_cg;
  const u32 ce = min(s_ce, (u32)EQCAP);
  const bool small = (ce <= 128u);

  auto sortnet = [&](u32& a, u32& b, bool asc) {
    const int lane = tid;
    for (int k = 2; k <= 128; k <<= 1) {
      for (int j = k >> 1; j > 0; j >>= 1) {
        if (j == 64) {
          bool up = ((lane & k) == 0) == asc;
          u32 lo = min(a, b), hi = max(a, b);
          a = up ? lo : hi;  b = up ? hi : lo;
        } else {
          bool upa = ((lane & k) == 0) == asc;
          bool upb = (((lane + 64) & k) == 0) == asc;
          bool lowa = (lane & j) == 0;
          u32 oa = (u32)__shfl_xor((int)a, j);
          u32 ob = (u32)__shfl_xor((int)b, j);
          a = (lowa == upa) ? min(a, oa) : max(a, oa);
          b = (lowa == upb) ? min(b, ob) : max(b, ob);
        }
      }
    }
  };

  if (tid < 64 && small) {
    u32 e0 = (tid < (int)ce) ? eqbuf[tid] : PADK;
    u32 e1 = (tid + 64 < (int)ce) ? eqbuf[tid + 64] : PADK;
    sortnet(e0, e1, false);
    eqbuf[tid] = e0; eqbuf[tid + 64] = e1;
  }
  __syncthreads();

  if (tid < 64) {
    if (!small) {
      for (u32 itn = 0; itn < needF; ++itn) {
        u32 mx = 0u;
        for (u32 i = tid; i < ce; i += 64) mx = max(mx, eqbuf[i]);
#pragma unroll
        for (int d = 32; d > 0; d >>= 1) mx = max(mx, (u32)__shfl_xor((int)mx, d));
        u32 fidx = 0xFFFFFFFFu;
        for (u32 i = tid; i < ce; i += 64) if (eqbuf[i] == mx) fidx = min(fidx, i);
#pragma unroll
        for (int d = 32; d > 0; d >>= 1) fidx = min(fidx, (u32)__shfl_xor((int)fidx, d));
        if (tid == (int)(fidx & 63u)) eqbuf[fidx] = 0u;
        if (tid == 0) grbuf[cg + itn] = mx;
      }
    }
    int i0 = tid, i1 = tid + 64;
    u32 m0, m1;
    if (small) {
      m0 = (i0 < (int)cg) ? grbuf[i0] : ((i0 < KTOP) ? eqbuf[i0 - cg] : PADK);
      m1 = (i1 < (int)cg) ? grbuf[i1] : ((i1 < KTOP) ? eqbuf[i1 - cg] : PADK);
    } else {
      m0 = (i0 < KTOP) ? grbuf[i0] : PADK;
      m1 = (i1 < KTOP) ? grbuf[i1] : PADK;
    }
    sortnet(m0, m1, true);
    float s = 0.f;
    if (i0 >= 28) {
      float a1 = float_of_key(m0);
      int t = i0 - 28;
      s += a1 * WA_w[t] + a1 * a1 * WA_w[KTOP + t];
    }
    {
      float a1 = float_of_key(m1);
      int t = i1 - 28;
      s += a1 * WA_w[t] + a1 * a1 * WA_w[KTOP + t];
    }
#pragma unroll
    for (int d = 32; d > 0; d >>= 1) s += __shfl_xor(s, d);
    if (tid == 0) Acmb[row_base + (int)blockIdx.x] = -(s + WA_b[0]);
  }
}

// ============================================================
// Threshold (rank select) + softmax over N -> Aw in out[1..N]
// ============================================================
__global__ __launch_bounds__(1024) void thr_softmax(
    const float* __restrict__ Acmb, float* __restrict__ out)
{
  __shared__ float vals[NTOK];
  __shared__ unsigned hist[256];
  __shared__ unsigned sufs[256];
  __shared__ float red[1024];
  __shared__ unsigned s_prefix, s_need;
  const int tid = threadIdx.x;
#pragma unroll
  for (int s = 0; s < 8; ++s) vals[tid + s * 1024] = Acmb[tid + s * 1024];
  if (tid == 0) { s_prefix = 0u; s_need = KTH_RANK; }
  __syncthreads();

  for (int pass = 3; pass >= 0; --pass) {
    if (tid < 256) hist[tid] = 0u;
    __syncthreads();
    unsigned pref  = s_prefix;
    unsigned pmask = (pass == 3) ? 0u : (0xFFFFFFFFu << ((pass + 1) * 8));
#pragma unroll
    for (int s = 0; s < 8; ++s) {
      unsigned key = key_of(vals[tid + s * 1024]);
      if ((key & pmask) == pref)
        atomicAdd(&hist[(key >> (pass * 8)) & 255u], 1u);
    }
    __syncthreads();
    if (tid < 256) sufs[tid] = hist[tid];
    __syncthreads();
    for (int off = 1; off < 256; off <<= 1) {
      unsigned add = 0u;
      if (tid < 256 && tid + off < 256) add = sufs[tid + off];
      __syncthreads();
      if (tid < 256) sufs[tid] += add;
      __syncthreads();
    }
    unsigned need = s_need;
    __syncthreads();
    if (tid < 256) {
      unsigned above = (tid == 255) ? 0u : sufs[tid + 1];
      if (sufs[tid] >= need && above < need) {
        s_prefix = pref | ((unsigned)tid << (pass * 8));
        s_need   = need - above;
      }
    }
    __syncthreads();
  }
  const float thre = float_of_key(s_prefix);

  float loc[8]; float mx = -1e30f;
#pragma unroll
  for (int s = 0; s < 8; ++s) {
    float v = vals[tid + s * 1024];
    v = (v > thre) ? v : 0.0f;
    loc[s] = v; mx = fmaxf(mx, v);
  }
  red[tid] = mx; __syncthreads();
  for (int off = 512; off > 0; off >>= 1) {
    if (tid < off) red[tid] = fmaxf(red[tid], red[tid + off]);
    __syncthreads();
  }
  float m = red[0]; __syncthreads();
  float sm = 0.0f;
#pragma unroll
  for (int s = 0; s < 8; ++s) sm += expf(loc[s] - m);
  red[tid] = sm; __syncthreads();
  for (int off = 512; off > 0; off >>= 1) {
    if (tid < off) red[tid] += red[tid + off];
    __syncthreads();
  }
  float Z = red[0];
#pragma unroll
  for (int s = 0; s < 8; ++s)
    out[1 + tid + s * 1024] = expf(loc[s] - m) / Z;
}

// ============================================================
__global__ __launch_bounds__(256) void z_partial(
    const float* __restrict__ aw, const float* __restrict__ query,
    float* __restrict__ zpart)
{
  const int g = blockIdx.x, t = threadIdx.x;
  float a0 = 0.f, a1 = 0.f;
  for (int r = 0; r < 64; ++r) {
    int n = g * 64 + r;
    float w = aw[n];
    const float* q = query + (size_t)n * HDIM;
    a0 = fmaf(w, q[t],       a0);
    a1 = fmaf(w, q[t + 256], a1);
  }
  zpart[(size_t)g * HDIM + t]       = a0;
  zpart[(size_t)g * HDIM + t + 256] = a1;
}

__global__ __launch_bounds__(512) void finalize(
    const float* __restrict__ zpart, const float* __restrict__ cls_w,
    const float* __restrict__ cls_b, float* __restrict__ out)
{
  __shared__ float red[512];
  const int t = threadIdx.x;
  float s = 0.f;
  for (int g = 0; g < 128; ++g) s += zpart[(size_t)g * HDIM + t];
  red[t] = s * cls_w[t];
  __syncthreads();
  for (int off = 256; off > 0; off >>= 1) {
    if (t < off) red[t] += red[t + off];
    __syncthreads();
  }
  if (t == 0) out[0] = red[0] + cls_b[0];
}

// ============================================================
extern "C" void kernel_launch(void* const* d_in, const int* in_sizes, int n_in,
                              void* d_out, int out_size, void* d_ws, size_t ws_size,
                              hipStream_t stream) {
  (void)in_sizes; (void)n_in; (void)out_size; (void)ws_size;
  const float* x_q   = (const float*)d_in[0];
  const float* x_k   = (const float*)d_in[1];
  const float* WQ_w  = (const float*)d_in[2];
  const float* WQ_b  = (const float*)d_in[3];
  const float* WK_w  = (const float*)d_in[4];
  const float* WK_b  = (const float*)d_in[5];
  const float* WA_w  = (const float*)d_in[6];
  const float* WA_b  = (const float*)d_in[7];
  const float* cls_w = (const float*)d_in[8];
  const float* cls_b = (const float*)d_in[9];
  float* out = (float*)d_out;
  char* base = (char*)d_ws;
  const size_t MB = 1u << 20;

  // Ach shrunk to 32 MB (CHUNK=1024): stays L3-resident across reuse,
  // so the A round-trip stops hitting HBM and B panels stay L3-hot.
  float* query = (float*)(base);               // 0..16 fp32 tanh(xWq+b)
  u16* qh      = (u16*)(base + 16 * MB);
  u16* ql      = (u16*)(base + 24 * MB);
  u16* kh      = (u16*)(base + 32 * MB);
  u16* kl      = (u16*)(base + 40 * MB);
  float* Ach   = (float*)(base + 48 * MB);     // 48..80 (32 MB)
  u16* wt_hi   = (u16*)(base + 80 * MB);
  u16* wt_lo   = (u16*)(base + 81 * MB);
  float* rq    = (float*)(base + 82 * MB);
  float* rk    = (float*)(base + 82 * MB + 65536);
  float* Acmb  = (float*)(base + 83 * MB);
  float* zpart = (float*)(base + 83 * MB + 65536);

  dim3 b256(256), b512(512);
  dim3 gproj(HDIM / 128, NTOK / 64);           // 4 x 128 = 512 blocks (FM=2)
  dim3 gchunk(NTOK / 128, CHUNK / 128);        // 64 x 8 = 512 blocks (FM=4)

  // --- projections with fused fp32->hi/lo split of x (no xsplit pass) ---
  wt_cast<<<dim3(16, 32), b256, 0, stream>>>(WQ_w, wt_hi, wt_lo);
  gemm_hl<1, 2><<<gproj, b512, 0, stream>>>(x_q, nullptr, nullptr, wt_hi, wt_lo,
      query, qh, ql, WQ_b, nullptr, nullptr, DIM, HDIM);
  wt_cast<<<dim3(16, 32), b256, 0, stream>>>(WK_w, wt_hi, wt_lo);
  gemm_hl<2, 2><<<gproj, b512, 0, stream>>>(x_k, nullptr, nullptr, wt_hi, wt_lo,
      nullptr, kh, kl, WK_b, nullptr, nullptr, DIM, HDIM);
  rownorm_inv<<<4096, b256, 0, stream>>>(qh, ql, kh, kl, rq, rk);
  // --- A chunks (L3-resident buffer) + fused exact top-100 -> Acmb ---
  for (int c = 0; c < NTOK / CHUNK; ++c) {
    gemm_hl<0, 4><<<gchunk, b512, 0, stream>>>(nullptr,
        qh + (size_t)c * CHUNK * HDIM, ql + (size_t)c * CHUNK * HDIM,
        kh, kl, Ach, nullptr, nullptr, nullptr, rq + c * CHUNK, rk, HDIM, NTOK);
    topk_acmb<<<CHUNK, b256, 0, stream>>>(Ach, WA_w, WA_b, Acmb, c * CHUNK);
  }
  thr_softmax<<<1, dim3(1024), 0, stream>>>(Acmb, out);
  z_partial<<<128, b256, 0, stream>>>(out + 1, query, zpart);
  finalize<<<1, dim3(512), 0, stream>>>(zpart, cls_w, cls_b, out);
}